// Round 1
// baseline (85.452 us; speedup 1.0000x reference)
//
#include <hip/hip_runtime.h>

// Problem constants (from reference): B=16, H=4, S=8, W=256, F=16
constexpr int Bc = 16;
constexpr int Hc = 4;
constexpr int Sc = 8;
constexpr int Wc = 256;
constexpr int Fc = 16;

// out[b,h,x,y,j,f] = (x!=y) ? conv(j)/(j+1) : (j>0 ? conv(j-1)/j : 0)
// where conv(r) = sum_{d=0..r} wrev[d] * X[r-d], wrev[d] = kernel[h,x,y,255-d],
// X[i] = x[b,x,i,:].
// Implemented uniformly by shifting X down by diag rows (zero row 0) and
// dividing by (j+1-diag).
__global__ __launch_bounds__(256)
void cc_kernel(const float* __restrict__ x,     // [B,S,W,F]
               const float* __restrict__ kern,  // [H,S,S,W]
               float* __restrict__ out)         // [B,H,S,S,W,F]
{
    __shared__ float Xs[Wc * Fc];       // 16 KB, diag-shifted x rows
    __shared__ float wpad[Wc + 16];     // wpad[16+d] = wrev[d]; wpad[0..15]=0

    int blk = blockIdx.x;
    const int sy = blk & 7;
    const int sx = (blk >> 3) & 7;
    const int h  = (blk >> 6) & 3;
    const int b  = blk >> 8;

    const int t = threadIdx.x;          // 0..255
    const int diag = (sx == sy) ? 1 : 0;

    // ---- stage reversed kernel row with 16-zero guard at the bottom ----
    {
        const float* kb = kern + ((h * Sc + sx) * Sc + sy) * Wc;
        wpad[16 + t] = kb[Wc - 1 - t];
        if (t < 16) wpad[t] = 0.0f;
    }
    // ---- stage X, shifted down by `diag` rows (row 0 zeroed if diag) ----
    {
        const float4* xsrc = reinterpret_cast<const float4*>(x + (b * Sc + sx) * Wc * Fc);
        float4* xdst = reinterpret_cast<float4*>(Xs);
        #pragma unroll
        for (int kk = 0; kk < 4; ++kk) {
            int q = t + 256 * kk;       // float4 index 0..1023
            int i = q >> 2;             // X row 0..255
            float4 v;
            if (i >= diag) v = xsrc[q - 4 * diag];
            else           v = make_float4(0.f, 0.f, 0.f, 0.f);
            xdst[q] = v;
        }
    }
    __syncthreads();

    const int f = t & 15;               // feature
    const int g = t >> 4;               // row group: rows 16g..16g+15

    float acc[16];
    #pragma unroll
    for (int r = 0; r < 16; ++r) acc[r] = 0.0f;

    // Sliding register window over wrev: for chunk ic,
    // wreg[k] = wpad[16*(g-ic) + k], k = 0..31  (covers d in [base16-16, base16+15])
    float wreg[32];
    {
        const float4* wp4 = reinterpret_cast<const float4*>(wpad + 16 * g);
        #pragma unroll
        for (int k4 = 0; k4 < 8; ++k4) {
            float4 v = wp4[k4];
            wreg[4 * k4 + 0] = v.x; wreg[4 * k4 + 1] = v.y;
            wreg[4 * k4 + 2] = v.z; wreg[4 * k4 + 3] = v.w;
        }
    }

    for (int ic = 0; ic <= g; ++ic) {
        #pragma unroll
        for (int ip = 0; ip < 16; ++ip) {
            float xv = Xs[(16 * ic + ip) * Fc + f];
            #pragma unroll
            for (int r = 0; r < 16; ++r) {
                // d = 16*(g-ic) + r - ip ; wreg index k = d - (base16-16) = 16+r-ip
                acc[r] = fmaf(wreg[16 + r - ip], xv, acc[r]);
            }
        }
        if (ic < g) {
            // shift window down by 16: upper half <- lower half, load new lower 16
            #pragma unroll
            for (int m = 0; m < 16; ++m) wreg[16 + m] = wreg[m];
            const float4* wp4 = reinterpret_cast<const float4*>(wpad + 16 * (g - ic - 1));
            #pragma unroll
            for (int k4 = 0; k4 < 4; ++k4) {
                float4 v = wp4[k4];
                wreg[4 * k4 + 0] = v.x; wreg[4 * k4 + 1] = v.y;
                wreg[4 * k4 + 2] = v.z; wreg[4 * k4 + 3] = v.w;
            }
        }
    }

    // ---- epilogue: divide and store ----
    float* ob = out + ((((b * Hc + h) * Sc + sx) * Sc + sy) * Wc) * Fc;
    #pragma unroll
    for (int r = 0; r < 16; ++r) {
        int j = 16 * g + r;
        int denom = j + 1 - diag;
        float val = (denom > 0) ? (acc[r] / (float)denom) : 0.0f;
        ob[j * Fc + f] = val;
    }
}

extern "C" void kernel_launch(void* const* d_in, const int* in_sizes, int n_in,
                              void* d_out, int out_size, void* d_ws, size_t ws_size,
                              hipStream_t stream) {
    const float* x    = (const float*)d_in[0];   // [B,S,W,F] = 524288 floats
    const float* kern = (const float*)d_in[1];   // [H,S,S,W] = 65536 floats
    float* out = (float*)d_out;                  // [B,H,S,S,W,F] = 16777216 floats

    const int nblocks = Bc * Hc * Sc * Sc;       // 4096
    cc_kernel<<<nblocks, 256, 0, stream>>>(x, kern, out);
}

// Round 2
// 32.128 us; speedup vs baseline: 2.6597x; 2.6597x over previous
//
#include <hip/hip_runtime.h>
#include <hip/hip_bf16.h>

typedef short short8 __attribute__((ext_vector_type(8)));
typedef float f32x4 __attribute__((ext_vector_type(4)));

union FragAB { int i[4]; short8 v; };

constexpr int Wc = 256, Fc = 16, Hc = 4, Sc = 8;

// ---------------- prep: x [B,S,W,F] fp32 -> xT [sx][(b,f)][k] bf16 in ws ----
__global__ __launch_bounds__(256)
void k_prep(const float* __restrict__ x, ushort* __restrict__ xT)
{
    __shared__ float xs[256 * 17];          // [k][f] padded
    const int blk = blockIdx.x;             // 0..127
    const int b = blk >> 3, sx = blk & 7;
    const int t = threadIdx.x;

    const float4* src = reinterpret_cast<const float4*>(x + (b * 8 + sx) * 4096);
    #pragma unroll
    for (int it = 0; it < 4; ++it) {
        int id = it * 256 + t;              // float4 id 0..1023
        float4 v = src[id];
        int k = id >> 2, fq = (id & 3) * 4;
        xs[k * 17 + fq + 0] = v.x;
        xs[k * 17 + fq + 1] = v.y;
        xs[k * 17 + fq + 2] = v.z;
        xs[k * 17 + fq + 3] = v.w;
    }
    __syncthreads();

    const int f = t >> 4, kc = (t & 15) * 16;
    int w[8];
    #pragma unroll
    for (int d = 0; d < 8; ++d) {
        float v0 = xs[(kc + 2 * d) * 17 + f];
        float v1 = xs[(kc + 2 * d + 1) * 17 + f];
        __hip_bfloat16 h0 = __float2bfloat16(v0);
        __hip_bfloat16 h1 = __float2bfloat16(v1);
        ushort u0 = reinterpret_cast<ushort&>(h0);
        ushort u1 = reinterpret_cast<ushort&>(h1);
        w[d] = (int)u0 | ((int)u1 << 16);
    }
    int4* dst = reinterpret_cast<int4*>(xT + (sx * 256 + b * 16 + f) * 256 + kc);
    dst[0] = make_int4(w[0], w[1], w[2], w[3]);
    dst[1] = make_int4(w[4], w[5], w[6], w[7]);
}

// ---------------- main: per (h,sx,sy,mt,nt) 128x128 MFMA tile -----------------
// out[j, n=(b,f)] = (1/(j+1-diag)) * sum_i wext[(320-diag)+j-i] * X[i, n]
// wext zero-padding handles both the triangular mask and the diagonal roll.
__global__ __launch_bounds__(256)
void k_main(const ushort* __restrict__ xT, const float* __restrict__ kern,
            float* __restrict__ out)
{
    __shared__ float wextf[576];
    __shared__ float rtab[256];
    __shared__ __align__(16) ushort Xts[128 * 264];  // 128 rows x (256 + 8 pad) bf16

    const int blk = blockIdx.x;             // 0..1023
    const int nt = blk & 1, mt = (blk >> 1) & 1, hxy = blk >> 2;
    const int sy = hxy & 7, sx = (hxy >> 3) & 7, h = hxy >> 6;
    const int diag = (sx == sy) ? 1 : 0;
    const int t = threadIdx.x;

    // reversed, zero-padded kernel row: wextf[320+d] = kern[h,sx,sy, 255-d]
    const float* krow = kern + ((h * Sc + sx) * Sc + sy) * Wc;
    #pragma unroll
    for (int q = 0; q < 3; ++q) {
        int idx = q * 256 + t;
        if (idx < 576) wextf[idx] = (idx >= 320) ? krow[575 - idx] : 0.0f;
    }
    // reciprocal table: 1/(j+1-diag), 0 when denom==0
    {
        int jd = t + 1 - diag;
        rtab[t] = (jd > 0) ? (1.0f / (float)jd) : 0.0f;
    }
    // stage X^T panel (128 n-rows x 256 k) into padded LDS
    {
        const int4* src = reinterpret_cast<const int4*>(xT + (sx * 256 + nt * 128) * 256);
        #pragma unroll
        for (int it = 0; it < 16; ++it) {
            int id = it * 256 + t;          // 16B-chunk id 0..4095
            int4 v = src[id];
            int nl = id >> 5, c = id & 31;
            *reinterpret_cast<int4*>(reinterpret_cast<char*>(Xts) + nl * 528 + c * 16) = v;
        }
    }
    __syncthreads();

    const int lane = t & 63, wid = t >> 6;
    const int wr = wid >> 1, wc = wid & 1;  // 2x2 waves over 128x128
    const int wm0 = mt * 128 + wr * 64;     // absolute output row base
    const int laneM = lane & 15, laneG = lane >> 4;

    // A element e of m-frag at K-step kc reads wextf[abase + 16m - kc - e]
    const int abase = (320 - diag) + wm0 + laneM - 8 * laneG;
    const char* bbase = reinterpret_cast<const char*>(Xts) + (wc * 64 + laneM) * 528 + laneG * 16;

    f32x4 zero = {0.0f, 0.0f, 0.0f, 0.0f};
    f32x4 acc[4][4];
    #pragma unroll
    for (int m = 0; m < 4; ++m)
        #pragma unroll
        for (int n = 0; n < 4; ++n) acc[m][n] = zero;

    const int kmax = (wm0 + 64 < 256) ? (wm0 + 64) : 256;   // triangle skip
    for (int kc = 0; kc < kmax; kc += 32) {
        FragAB bf[4];
        #pragma unroll
        for (int n = 0; n < 4; ++n) {
            int4 raw = *reinterpret_cast<const int4*>(bbase + n * (16 * 528) + kc * 2);
            bf[n].i[0] = raw.x; bf[n].i[1] = raw.y; bf[n].i[2] = raw.z; bf[n].i[3] = raw.w;
        }
        FragAB af[4];
        #pragma unroll
        for (int m = 0; m < 4; ++m) {
            int idx0 = abase + 16 * m - kc;
            float v[8];
            #pragma unroll
            for (int e = 0; e < 8; ++e) v[e] = wextf[idx0 - e];
            #pragma unroll
            for (int r = 0; r < 4; ++r)
                af[m].i[r] = (int)__builtin_amdgcn_perm(__float_as_uint(v[2 * r + 1]),
                                                        __float_as_uint(v[2 * r]),
                                                        0x07060302u);
        }
        #pragma unroll
        for (int m = 0; m < 4; ++m)
            #pragma unroll
            for (int n = 0; n < 4; ++n)
                acc[m][n] = __builtin_amdgcn_mfma_f32_16x16x32_bf16(af[m].v, bf[n].v,
                                                                    acc[m][n], 0, 0, 0);
    }

    // epilogue: scale by 1/(j+1-diag) and store
    #pragma unroll
    for (int n = 0; n < 4; ++n) {
        int b_ = nt * 8 + wc * 4 + n;
        float* ob = out + ((((b_ * Hc + h) * Sc + sx) * Sc + sy) * Wc) * Fc + laneM;
        #pragma unroll
        for (int m = 0; m < 4; ++m) {
            int jb = wm0 + 16 * m + laneG * 4;
            #pragma unroll
            for (int r = 0; r < 4; ++r) {
                int j = jb + r;
                ob[j * 16] = acc[m][n][r] * rtab[j];
            }
        }
    }
}

extern "C" void kernel_launch(void* const* d_in, const int* in_sizes, int n_in,
                              void* d_out, int out_size, void* d_ws, size_t ws_size,
                              hipStream_t stream) {
    const float* x    = (const float*)d_in[0];   // [16,8,256,16]
    const float* kern = (const float*)d_in[1];   // [4,8,8,256]
    float* out = (float*)d_out;                  // [16,4,8,8,256,16]
    ushort* xT = (ushort*)d_ws;                  // 1 MB bf16 scratch

    k_prep<<<128, 256, 0, stream>>>(x, xT);
    k_main<<<1024, 256, 0, stream>>>(xT, kern, out);
}

// Round 3
// 24.228 us; speedup vs baseline: 3.5269x; 1.3261x over previous
//
#include <hip/hip_runtime.h>
#include <hip/hip_bf16.h>

typedef short short8 __attribute__((ext_vector_type(8)));
typedef float f32x4 __attribute__((ext_vector_type(4)));

union FragAB { int i[4]; short8 v; };

constexpr int Wc = 256, Fc = 16, Hc = 4, Sc = 8;

// Fused kernel. Block = (sx, mt, nt, c): stages the (sx,nt) X-panel once
// (fp32 -> bf16 transpose in-kernel), then computes TWO (h,sy) output tiles
// (hy = 2c, 2c+1) of 128 rows (mt half) x 128 cols (nt half).
//
// out[j, n=(b,f)] = rtab[diag][j] * sum_i wext[(320-diag)+j-i] * X[i,n]
// wext zero-padding below 320 implements both the triangular mask and the
// diagonal roll-by-one (offset 319 + divide by j instead of j+1).
__global__ __launch_bounds__(256)
void k_fused(const float* __restrict__ x,     // [B=16, S=8, W=256, F=16]
             const float* __restrict__ kern,  // [H=4, S=8, S=8, W=256]
             float* __restrict__ out)         // [B,H,S,S,W,F]
{
    __shared__ __align__(16) ushort Xts[128 * 264];  // [n-local][k], row stride 528 B
    __shared__ float wext2[2][576];
    __shared__ float rtab[2][256];

    const int blk = blockIdx.x;             // 0..511
    const int c  = blk & 15;                // hy chunk (2 per block)
    const int nt = (blk >> 4) & 1;
    const int mt = (blk >> 5) & 1;
    const int sx = blk >> 6;
    const int t = threadIdx.x;

    // ---- reciprocal tables ----
    rtab[0][t] = 1.0f / (float)(t + 1);
    rtab[1][t] = (t > 0) ? 1.0f / (float)t : 0.0f;

    // ---- both reversed/zero-padded kernel rows ----
    #pragma unroll
    for (int e2 = 0; e2 < 2; ++e2) {
        int hy = c * 2 + e2;
        int h = hy >> 3, sy = hy & 7;
        const float* krow = kern + ((h * Sc + sx) * Sc + sy) * Wc;
        #pragma unroll
        for (int q = 0; q < 3; ++q) {
            int idx = q * 256 + t;
            if (idx < 576) wext2[e2][idx] = (idx >= 320) ? krow[575 - idx] : 0.0f;
        }
    }

    // ---- stage + transpose x slice -> Xts (bf16) ----
    // Xts[(b-b0)*16 + f][k] = bf16(x[b, sx, k, f]), b0 = nt*8
    {
        const float4* xbase = reinterpret_cast<const float4*>(x);
        const int b0 = nt * 8;
        #pragma unroll
        for (int it = 0; it < 16; ++it) {
            int id = it * 256 + t;              // 0..4095
            int fq = id & 3;                    // f quad
            int k2 = (id >> 2) & 127;           // k pair
            int bl = id >> 9;                   // local b 0..7
            const float4* rowp = xbase + ((size_t)((b0 + bl) * 8 + sx)) * 1024;
            float4 a = rowp[(2 * k2) * 4 + fq];
            float4 cq = rowp[(2 * k2 + 1) * 4 + fq];
            #pragma unroll
            for (int e = 0; e < 4; ++e) {
                float va = (&a.x)[e], vb = (&cq.x)[e];
                __hip_bfloat16 ha = __float2bfloat16(va);
                __hip_bfloat16 hb = __float2bfloat16(vb);
                uint u = (uint)reinterpret_cast<ushort&>(ha) |
                         ((uint)reinterpret_cast<ushort&>(hb) << 16);
                int row = bl * 16 + fq * 4 + e;
                *reinterpret_cast<uint*>(reinterpret_cast<char*>(Xts) + row * 528 + k2 * 4) = u;
            }
        }
    }
    __syncthreads();

    const int lane = t & 63, wid = t >> 6;
    const int wr = wid >> 1, wc = wid & 1;      // 2x2 waves over 128x128
    const int wm0 = mt * 128 + wr * 64;         // absolute output row base
    const int laneM = lane & 15, laneG = lane >> 4;

    const char* bbase = reinterpret_cast<const char*>(Xts) + (wc * 64 + laneM) * 528 + laneG * 16;
    const int kmax = (wm0 + 64 < 256) ? (wm0 + 64) : 256;    // triangle skip

    #pragma unroll
    for (int e2 = 0; e2 < 2; ++e2) {
        int hy = c * 2 + e2;
        int h = hy >> 3, sy = hy & 7;
        const int diag = (sx == sy) ? 1 : 0;
        const float* wextf = wext2[e2];
        const float* rt = rtab[diag];
        // A element e of m-frag at K-step kc reads wextf[abase + 16m - kc - e]
        const int abase = (320 - diag) + wm0 + laneM - 8 * laneG;

        f32x4 zero = {0.0f, 0.0f, 0.0f, 0.0f};
        f32x4 acc[4][4];
        #pragma unroll
        for (int m = 0; m < 4; ++m)
            #pragma unroll
            for (int n = 0; n < 4; ++n) acc[m][n] = zero;

        for (int kc = 0; kc < kmax; kc += 32) {
            FragAB bf[4];
            #pragma unroll
            for (int n = 0; n < 4; ++n) {
                int4 raw = *reinterpret_cast<const int4*>(bbase + n * (16 * 528) + kc * 2);
                bf[n].i[0] = raw.x; bf[n].i[1] = raw.y; bf[n].i[2] = raw.z; bf[n].i[3] = raw.w;
            }
            FragAB af[4];
            #pragma unroll
            for (int m = 0; m < 4; ++m) {
                int idx0 = abase + 16 * m - kc;
                float v[8];
                #pragma unroll
                for (int e = 0; e < 8; ++e) v[e] = wextf[idx0 - e];
                #pragma unroll
                for (int r = 0; r < 4; ++r)
                    af[m].i[r] = (int)__builtin_amdgcn_perm(__float_as_uint(v[2 * r + 1]),
                                                            __float_as_uint(v[2 * r]),
                                                            0x07060302u);
            }
            #pragma unroll
            for (int m = 0; m < 4; ++m)
                #pragma unroll
                for (int n = 0; n < 4; ++n)
                    acc[m][n] = __builtin_amdgcn_mfma_f32_16x16x32_bf16(af[m].v, bf[n].v,
                                                                        acc[m][n], 0, 0, 0);
        }

        // epilogue: scale and store
        #pragma unroll
        for (int n = 0; n < 4; ++n) {
            int b_ = nt * 8 + wc * 4 + n;
            float* ob = out + ((((((size_t)b_ * Hc + h) * Sc + sx) * Sc + sy) * Wc)) * Fc + laneM;
            #pragma unroll
            for (int m = 0; m < 4; ++m) {
                int jb = wm0 + 16 * m + laneG * 4;
                #pragma unroll
                for (int r = 0; r < 4; ++r) {
                    int j = jb + r;
                    ob[(size_t)j * 16] = acc[m][n][r] * rt[j];
                }
            }
        }
    }
}

extern "C" void kernel_launch(void* const* d_in, const int* in_sizes, int n_in,
                              void* d_out, int out_size, void* d_ws, size_t ws_size,
                              hipStream_t stream) {
    const float* x    = (const float*)d_in[0];   // [16,8,256,16]
    const float* kern = (const float*)d_in[1];   // [4,8,8,256]
    float* out = (float*)d_out;                  // [16,4,8,8,256,16]

    k_fused<<<512, 256, 0, stream>>>(x, kern, out);
}